// Round 4
// baseline (890.645 us; speedup 1.0000x reference)
//
#include <hip/hip_runtime.h>

typedef unsigned short u16;
typedef __attribute__((ext_vector_type(8))) short bf16x8;
typedef __attribute__((ext_vector_type(4))) short bf16x4;
typedef __attribute__((ext_vector_type(4))) float f32x4;

#define MFMA16(a,b,c) __builtin_amdgcn_mfma_f32_16x16x32_bf16(a,b,c,0,0,0)

__device__ __forceinline__ float bf2f(short s){
  return __uint_as_float(((unsigned)(u16)s) << 16);
}
__device__ __forceinline__ short f2bf(float f){
  unsigned u = __float_as_uint(f);
  return (short)((u + 0x7FFFu + ((u >> 16) & 1u)) >> 16);
}
__device__ __forceinline__ void gload16(const void* g, void* l){
  __builtin_amdgcn_global_load_lds((const __attribute__((address_space(1))) unsigned int*)g,
                                   (__attribute__((address_space(3))) unsigned int*)l, 16, 0, 0);
}
__device__ __forceinline__ float silu_f(float v){ return v / (1.f + __expf(-v)); }

// ---------------------------------------------------------------- fp32 -> bf16
__global__ __launch_bounds__(256) void cvt_kernel(const float* __restrict__ s, u16* __restrict__ d){
  size_t i = ((size_t)blockIdx.x*256 + threadIdx.x)*8;
  float4 a = *(const float4*)(s+i);
  float4 b = *(const float4*)(s+i+4);
  bf16x8 o;
  o[0]=f2bf(a.x); o[1]=f2bf(a.y); o[2]=f2bf(a.z); o[3]=f2bf(a.w);
  o[4]=f2bf(b.x); o[5]=f2bf(b.y); o[6]=f2bf(b.z); o[7]=f2bf(b.w);
  *(bf16x8*)(d+i) = o;
}

// ---------------------------------------------------------------- GEMM C = A * B^T (m97 structure)
// A[M][1024] bf16, Bw[N][1024] bf16 (rows = output channels). 128x128 tile, BK=64, 4 waves.
// MODE 0: QKV epilogue (nblk 0-7 -> q [tok][ch] with silu; 8-15 -> kT [ch][tok] silu; 16-23 -> vT no silu)
// MODE 1: fp32 out [tok][ch]
template<int MODE>
__global__ __launch_bounds__(256) void gemm_bt(
    const u16* __restrict__ A, const u16* __restrict__ Bw,
    u16* __restrict__ qo, u16* __restrict__ kTo, u16* __restrict__ vTo,
    float* __restrict__ outf)
{
  __shared__ __align__(16) char smem[65536];   // 2 x (A 16K | B 16K)
  const int tid = threadIdx.x, l = tid & 63, wv = tid >> 6;
  const int m0 = blockIdx.y << 7, n0 = blockIdx.x << 7;
  const int wr = wv >> 1, wc = wv & 1;
  const int srow = wv*8 + (l>>3);        // + i*32
  const int scol = (l&7)*8;              // u16 units (16B)

  f32x4 acc[4][4] = {};

  { // prologue stage buf0, kt=0
    const u16* Ab = A + (size_t)m0*1024;
    const u16* Bb = Bw + (size_t)n0*1024;
    #pragma unroll
    for (int i=0;i<4;i++){
      gload16(Ab + (size_t)(srow + i*32)*1024 + scol, smem + i*4096 + wv*1024);
      gload16(Bb + (size_t)(srow + i*32)*1024 + scol, smem + 16384 + i*4096 + wv*1024);
    }
  }
  for (int kt=0; kt<16; ++kt){
    __syncthreads();
    if (kt+1 < 16){
      const int k0 = (kt+1)*64;
      const u16* Ab = A + (size_t)m0*1024 + k0;
      const u16* Bb = Bw + (size_t)n0*1024 + k0;
      char* lb = smem + ((kt+1)&1)*32768;
      #pragma unroll
      for (int i=0;i<4;i++){
        gload16(Ab + (size_t)(srow + i*32)*1024 + scol, lb + i*4096 + wv*1024);
        gload16(Bb + (size_t)(srow + i*32)*1024 + scol, lb + 16384 + i*4096 + wv*1024);
      }
    }
    const char* la  = smem + (kt&1)*32768;
    const char* lbB = la + 16384;
    #pragma unroll
    for (int ks=0; ks<2; ++ks){
      const int kb = ks*64 + ((l>>4)<<4);
      bf16x8 af[4], bfr[4];
      #pragma unroll
      for (int t=0;t<4;t++){
        af[t]  = *(const bf16x8*)(la  + (wr*64 + t*16 + (l&15))*128 + kb);
        bfr[t] = *(const bf16x8*)(lbB + (wc*64 + t*16 + (l&15))*128 + kb);
      }
      #pragma unroll
      for (int i=0;i<4;i++)
        #pragma unroll
        for (int j=0;j<4;j++)
          acc[i][j] = MFMA16(af[i], bfr[j], acc[i][j]);
    }
  }
  // epilogue: D layout col = l&15, row = (l>>4)*4 + r
  if constexpr (MODE == 1){
    #pragma unroll
    for (int i=0;i<4;i++){
      const int tok = m0 + wr*64 + i*16 + ((l>>4)<<2);
      #pragma unroll
      for (int j=0;j<4;j++){
        const int ch = n0 + wc*64 + j*16 + (l&15);
        #pragma unroll
        for (int r=0;r<4;r++)
          outf[(size_t)(tok+r)*1024 + ch] = acc[i][j][r];
      }
    }
  } else {
    const int nblk = blockIdx.x;
    if (nblk < 8){
      #pragma unroll
      for (int i=0;i<4;i++){
        const int tok = m0 + wr*64 + i*16 + ((l>>4)<<2);
        #pragma unroll
        for (int j=0;j<4;j++){
          const int ch = (nblk<<7) + wc*64 + j*16 + (l&15);
          #pragma unroll
          for (int r=0;r<4;r++)
            qo[(size_t)(tok+r)*1024 + ch] = (u16)f2bf(silu_f(acc[i][j][r]));
        }
      }
    } else {
      const bool dos = nblk < 16;             // k gets silu, v not
      u16* T = dos ? kTo : vTo;
      const int cb = (nblk - (dos?8:16))<<7;
      #pragma unroll
      for (int i=0;i<4;i++){
        const int tok0 = m0 + wr*64 + i*16 + ((l>>4)<<2);
        #pragma unroll
        for (int j=0;j<4;j++){
          const int ch = cb + wc*64 + j*16 + (l&15);
          bf16x4 pk;
          #pragma unroll
          for (int r=0;r<4;r++){
            float v = acc[i][j][r];
            if (dos) v = silu_f(v);
            pk[r] = f2bf(v);
          }
          *(bf16x4*)(T + (size_t)ch*32768 + tok0) = pk;   // transposed [ch][tok]
        }
      }
    }
  }
}

// ---------------------------------------------------------------- log_f = logsigmoid(x @ Wf^T + delta)
__global__ __launch_bounds__(256) void logf_kernel(
  const u16* __restrict__ xbf, const u16* __restrict__ wf,
  const float* __restrict__ delta, float* __restrict__ lfo)
{
  const int tid = threadIdx.x, l = tid&63, wv = tid>>6;
  const int arow = blockIdx.x*64 + wv*16 + (l&15);
  const u16* xr  = xbf + (size_t)arow*1024 + ((l>>4)<<3);
  const u16* wr_ = wf  + (size_t)(l&15)*1024 + ((l>>4)<<3);
  f32x4 acc = {0.f,0.f,0.f,0.f};
  #pragma unroll 4
  for (int kk=0; kk<32; ++kk){
    bf16x8 a = *(const bf16x8*)(xr  + kk*32);
    bf16x8 b = *(const bf16x8*)(wr_ + kk*32);
    acc = MFMA16(a,b,acc);
  }
  const int h = l&15;
  const float dl = delta[h];
  const int trow = blockIdx.x*64 + wv*16 + ((l>>4)<<2);
  #pragma unroll
  for (int r=0;r<4;r++){
    float z = acc[r] + dl;
    lfo[(size_t)(trow + r)*16 + h] = fminf(z, 0.f) - log1pf(__expf(-fabsf(z)));
  }
}

// ---------------------------------------------------------------- per-chunk intra kernel
// LDS map: [0,16K) s_q [128][64] swz8 ; [16K,32K) s_k [128][64] swz8 (built by identity-mfma)
//          [32K,48K) s_kT [64][128] swz16 ; [48K,64K) s_vT [64][128] swz16
//          AA overlays [0,32K) as [128][128] bf16 swz16 ; Bc-bounce overlays [32K,48K) f32 [64][64] swz16
#define P2_SK  16384
#define P2_SKT 32768
#define P2_SVT 49152
__global__ __launch_bounds__(256) void intra_kernel(
  u16* __restrict__ q,
  const u16* __restrict__ kT, const u16* __restrict__ vT,
  const float* __restrict__ lfin, float* __restrict__ tots,
  u16* __restrict__ O, float* __restrict__ BT)
{
  __shared__ __align__(16) char smem[67072];
  float* s_lf = (float*)(smem + 65536);
  float* s_e  = (float*)(smem + 66048);
  float* s_en = (float*)(smem + 66560);
  const int c = blockIdx.x, bh = blockIdx.y;
  const int b = bh >> 4, h = bh & 15;
  const int tid = threadIdx.x, l = tid&63, wv = tid>>6;
  const size_t tok0 = (size_t)b*8192 + (size_t)c*128;

  // Phase A: inclusive cumsum of log_f, gates
  if (tid < 128) s_lf[tid] = lfin[(tok0 + tid)*16 + h];
  __syncthreads();
  #pragma unroll
  for (int off=1; off<128; off<<=1){
    float v = 0.f;
    if (tid < 128) v = s_lf[tid] + ((tid >= off) ? s_lf[tid-off] : 0.f);
    __syncthreads();
    if (tid < 128) s_lf[tid] = v;
    __syncthreads();
  }
  if (tid < 128){ const float lv = s_lf[tid]; s_e[tid] = __expf(lv); s_en[tid] = __expf(-lv); }
  if (tid == 0) tots[((size_t)b*16 + h)*64 + c] = s_lf[127];
  __syncthreads();

  // Phase B: stage q (and write qg=q*e[j] back), kT*en[j] -> s_kT, vT -> s_vT
  {
    u16* qb = q + tok0*1024 + h*64;
    #pragma unroll
    for (int it=0; it<4; ++it){
      const int cid = it*256 + tid;
      const int j = cid >> 3, d0 = (cid&7)*8;
      bf16x8 v = *(const bf16x8*)(qb + (size_t)j*1024 + d0);
      *(bf16x8*)(smem + j*128 + ((d0*2) ^ ((j&7)<<4))) = v;
      const float ej = s_e[j];
      bf16x8 o;
      #pragma unroll
      for (int u=0;u<8;u++) o[u] = f2bf(bf2f(v[u]) * ej);
      *(bf16x8*)(qb + (size_t)j*1024 + d0) = o;
    }
    const u16* kb_ = kT + (size_t)(h*64)*32768 + tok0;
    const u16* vb_ = vT + (size_t)(h*64)*32768 + tok0;
    #pragma unroll
    for (int it=0; it<4; ++it){
      const int cid = it*256 + tid;
      const int d = cid >> 4, j0 = (cid&15)*8;
      bf16x8 kv = *(const bf16x8*)(kb_ + (size_t)d*32768 + j0);
      bf16x8 vv = *(const bf16x8*)(vb_ + (size_t)d*32768 + j0);
      bf16x8 ks;
      #pragma unroll
      for (int u=0;u<8;u++) ks[u] = f2bf(bf2f(kv[u]) * s_en[j0+u]);
      *(bf16x8*)(smem + P2_SKT + d*256 + ((j0*2) ^ ((d&15)<<4))) = ks;
      *(bf16x8*)(smem + P2_SVT + d*256 + ((j0*2) ^ ((d&15)<<4))) = vv;
    }
  }
  __syncthreads();

  // Phase C: identity-MFMA transpose s_kT[64][128] -> s_k[128][64]
  #pragma unroll
  for (int nn=0; nn<2; ++nn){
    const int nt = wv*2 + nn;                 // j-tile 0..7
    const int kk = nt >> 1;
    const int ustar = ((nt&1)<<4) + (l&15) - ((l>>4)<<3);
    bf16x8 ib;
    #pragma unroll
    for (int u=0;u<8;u++) ib[u] = (u == ustar) ? (short)0x3F80 : (short)0;
    const int jb = (kk*32 + ((l>>4)<<3))*2;
    #pragma unroll
    for (int mt=0; mt<4; ++mt){
      const int d = mt*16 + (l&15);
      bf16x8 af = *(const bf16x8*)(smem + P2_SKT + d*256 + (jb ^ ((d&15)<<4)));
      f32x4 dd = {0.f,0.f,0.f,0.f};
      dd = MFMA16(af, ib, dd);
      const int jj = nt*16 + (l&15);
      const int d0 = mt*16 + ((l>>4)<<2);
      bf16x4 pk;
      #pragma unroll
      for (int r=0;r<4;r++) pk[r] = f2bf(dd[r]);
      *(bf16x4*)(smem + P2_SK + jj*128 + ((d0*2) ^ ((jj&7)<<4))) = pk;
    }
  }
  __syncthreads();

  // Phase D: D1 = ks * q^T  (D1[j][i] = A[i][j]*en[j]); wave w owns j-tiles {w, 7-w}
  f32x4 acc1[2][8] = {};
  const int jt0 = wv, jt1 = 7 - wv;
  #pragma unroll
  for (int ks=0; ks<2; ++ks){
    const int kb = (ks*32 + ((l>>4)<<3))*2;
    bf16x8 aq[8];
    #pragma unroll
    for (int nt=0;nt<8;nt++){
      const int i = nt*16 + (l&15);
      aq[nt] = *(const bf16x8*)(smem + i*128 + (kb ^ ((i&7)<<4)));
    }
    const int jr0 = jt0*16 + (l&15), jr1 = jt1*16 + (l&15);
    bf16x8 ak0 = *(const bf16x8*)(smem + P2_SK + jr0*128 + (kb ^ ((jr0&7)<<4)));
    bf16x8 ak1 = *(const bf16x8*)(smem + P2_SK + jr1*128 + (kb ^ ((jr1&7)<<4)));
    #pragma unroll
    for (int nt=0;nt<8;nt++){
      if (nt >= jt0) acc1[0][nt] = MFMA16(ak0, aq[nt], acc1[0][nt]);
      if (nt >= jt1) acc1[1][nt] = MFMA16(ak1, aq[nt], acc1[1][nt]);
    }
  }
  __syncthreads();          // all reads of [0,32K) done

  // Phase D2: gate (* e[i], tril mask), write AA[i][j] bf16 over [0,32K)
  #pragma unroll
  for (int jj=0;jj<2;jj++){
    const int jt = (jj==0)? jt0 : jt1;
    const int j0 = jt*16 + ((l>>4)<<2);
    #pragma unroll
    for (int nt=0;nt<8;nt++){
      const int i = nt*16 + (l&15);
      bf16x4 pk;
      if (nt < jt){
        #pragma unroll
        for (int r=0;r<4;r++) pk[r] = (short)0;
      } else {
        const float ei = s_e[i];
        #pragma unroll
        for (int r=0;r<4;r++){
          float v = acc1[jj][nt][r] * ei;
          if (nt == jt && (j0 + r) > i) v = 0.f;
          pk[r] = f2bf(v);
        }
      }
      *(bf16x4*)(smem + i*256 + ((j0*2) ^ ((i&15)<<4))) = pk;
    }
  }
  __syncthreads();

  // Phase E: o_intra^T[e][i] = sum_j vT[e][j]*AA[i][j]  (wave owns i-tiles {w,7-w})
  //          Bc[d][e]        = sum_j kT[d][j]*vT[e][j]  (wave owns d-tile w)
  {
    const int nt0 = wv, nt1 = 7 - wv;
    f32x4 oacc[2][4] = {};
    f32x4 bcacc[4] = {};
    #pragma unroll
    for (int kk=0; kk<4; ++kk){
      const int jb = (kk*32 + ((l>>4)<<3))*2;
      bf16x8 av[4];
      #pragma unroll
      for (int mt=0;mt<4;mt++){
        const int e = mt*16 + (l&15);
        av[mt] = *(const bf16x8*)(smem + P2_SVT + e*256 + (jb ^ ((e&15)<<4)));
      }
      const int dr = wv*16 + (l&15);
      bf16x8 akt = *(const bf16x8*)(smem + P2_SKT + dr*256 + (jb ^ ((dr&15)<<4)));
      #pragma unroll
      for (int mt=0;mt<4;mt++) bcacc[mt] = MFMA16(akt, av[mt], bcacc[mt]);
      const int i0 = nt0*16 + (l&15);
      if (kk <= (nt0>>1)){
        bf16x8 ba = *(const bf16x8*)(smem + i0*256 + (jb ^ ((i0&15)<<4)));
        #pragma unroll
        for (int mt=0;mt<4;mt++) oacc[0][mt] = MFMA16(av[mt], ba, oacc[0][mt]);
      }
      const int i1 = nt1*16 + (l&15);
      if (kk <= (nt1>>1)){
        bf16x8 ba = *(const bf16x8*)(smem + i1*256 + (jb ^ ((i1&15)<<4)));
        #pragma unroll
        for (int mt=0;mt<4;mt++) oacc[1][mt] = MFMA16(av[mt], ba, oacc[1][mt]);
      }
    }
    // store o_intra (bf16, 8B packed along e)
    #pragma unroll
    for (int jj=0;jj<2;jj++){
      const int nt = (jj==0)?nt0:nt1;
      const int i = nt*16 + (l&15);
      u16* orow = O + (tok0 + i)*1024 + h*64;
      #pragma unroll
      for (int mt=0;mt<4;mt++){
        const int e0 = mt*16 + ((l>>4)<<2);
        bf16x4 pk;
        #pragma unroll
        for (int r=0;r<4;r++) pk[r] = f2bf(oacc[jj][mt][r]);
        *(bf16x4*)(orow + e0) = pk;
      }
    }
    __syncthreads();    // s_kT reads done
    // E2: Bc -> LDS bounce (layout [e][d] f32, swizzled) over s_kT region, then coalesced store
    #pragma unroll
    for (int nt2=0; nt2<4; ++nt2){
      const int e = nt2*16 + (l&15);
      const int d0 = wv*16 + ((l>>4)<<2);
      *(f32x4*)(smem + P2_SKT + e*256 + ((d0*4) ^ ((e&15)<<4))) = bcacc[nt2];
    }
    __syncthreads();
    float* BTo = BT + (((size_t)c*4 + b)*16 + h)*4096;
    #pragma unroll
    for (int u=0;u<4;u++){
      const int fb = tid*64 + u*16;
      const int e = fb >> 8, wi = fb & 255;
      f32x4 vvv = *(const f32x4*)(smem + P2_SKT + e*256 + (wi ^ ((e&15)<<4)));
      *(f32x4*)((char*)BTo + fb) = vvv;
    }
  }
}

// ---------------------------------------------------------------- sequential scalar-decay scan
// BT/ST layout: [c][b][h][e*64+d] ; ST[c] = state BEFORE chunk c (bf16); S <- e^tot * (S + Bc)
__global__ __launch_bounds__(256) void scan_kernel(
  const float* __restrict__ BT, const float* __restrict__ tots, u16* __restrict__ ST)
{
  const int blk = blockIdx.x;
  const int bh = blk >> 2, qt = blk & 3;
  const int tid = threadIdx.x;
  __shared__ float s_tot[64];
  if (tid < 64) s_tot[tid] = tots[(size_t)bh*64 + tid];
  __syncthreads();
  const int flat = qt*1024 + tid*4;
  const float* bp = BT + (size_t)bh*4096 + flat;
  u16* sp = ST + (size_t)bh*4096 + flat;
  const size_t cs = 262144;
  f32x4 S = {0.f,0.f,0.f,0.f};
  f32x4 cur = *(const f32x4*)bp;
  f32x4 nxt = *(const f32x4*)(bp + cs);
  for (int cc=0; cc<64; ++cc){
    bf16x4 pk;
    #pragma unroll
    for (int r=0;r<4;r++) pk[r] = f2bf(S[r]);
    *(bf16x4*)(sp + (size_t)cc*cs) = pk;
    const float et = __expf(s_tot[cc]);
    #pragma unroll
    for (int r=0;r<4;r++) S[r] = et*(S[r] + cur[r]);
    cur = nxt;
    if (cc + 2 < 64) nxt = *(const f32x4*)(bp + (size_t)(cc+2)*cs);
  }
}

// ---------------------------------------------------------------- o_inter = qg @ S, RMW into O
__global__ __launch_bounds__(256) void inter_kernel(
  const u16* __restrict__ qg, const u16* __restrict__ ST, u16* __restrict__ O)
{
  __shared__ __align__(16) char smem[24576];   // s_qg [128][64] swz8 @0 ; s_ST [64][64] swz8 @16384
  const int c = blockIdx.x, bh = blockIdx.y;
  const int b = bh>>4, h = bh&15;
  const int tid = threadIdx.x, l = tid&63, wv = tid>>6;
  const size_t tok0 = (size_t)b*8192 + (size_t)c*128;
  const u16* qb = qg + tok0*1024 + h*64;
  #pragma unroll
  for (int it=0; it<4; ++it){
    const int cid = it*256 + tid, j = cid>>3, d0 = (cid&7)*8;
    bf16x8 v = *(const bf16x8*)(qb + (size_t)j*1024 + d0);
    *(bf16x8*)(smem + j*128 + ((d0*2) ^ ((j&7)<<4))) = v;
  }
  const u16* stb = ST + (((size_t)c*4 + b)*16 + h)*4096;
  #pragma unroll
  for (int it=0; it<2; ++it){
    const int cid = it*256 + tid, e = cid>>3, d0 = (cid&7)*8;
    bf16x8 v = *(const bf16x8*)(stb + (size_t)e*64 + d0);
    *(bf16x8*)(smem + 16384 + e*128 + ((d0*2) ^ ((e&7)<<4))) = v;
  }
  __syncthreads();
  f32x4 acc[8] = {};
  #pragma unroll
  for (int ks=0; ks<2; ++ks){
    const int kb = (ks*32 + ((l>>4)<<3))*2;
    const int er = wv*16 + (l&15);
    bf16x8 as = *(const bf16x8*)(smem + 16384 + er*128 + (kb ^ ((er&7)<<4)));
    #pragma unroll
    for (int nt=0;nt<8;nt++){
      const int ir = nt*16 + (l&15);
      bf16x8 bq = *(const bf16x8*)(smem + ir*128 + (kb ^ ((ir&7)<<4)));
      acc[nt] = MFMA16(as, bq, acc[nt]);
    }
  }
  const int e0 = wv*16 + ((l>>4)<<2);
  #pragma unroll
  for (int nt=0;nt<8;nt++){
    const int i = nt*16 + (l&15);
    u16* op = O + (tok0 + i)*1024 + h*64 + e0;
    bf16x4 cu = *(const bf16x4*)op;
    bf16x4 pk;
    #pragma unroll
    for (int r=0;r<4;r++) pk[r] = f2bf(bf2f(cu[r]) + acc[nt][r]);
    *(bf16x4*)op = pk;
  }
}

// ---------------------------------------------------------------- RMSNorm (one wave per token)
__global__ __launch_bounds__(256) void rmsnorm_kernel(
  const u16* __restrict__ O, const float* __restrict__ nw, u16* __restrict__ ON)
{
  const int tid = threadIdx.x, l = tid&63, wv = tid>>6;
  const size_t tok = (size_t)blockIdx.x*4 + wv;
  const u16* row = O + tok*1024;
  bf16x8 v0 = *(const bf16x8*)(row + l*8);
  bf16x8 v1 = *(const bf16x8*)(row + 512 + l*8);
  float f0[8], f1[8];
  float ss = 0.f;
  #pragma unroll
  for (int u=0;u<8;u++){ f0[u]=bf2f(v0[u]); f1[u]=bf2f(v1[u]); ss += f0[u]*f0[u] + f1[u]*f1[u]; }
  #pragma unroll
  for (int off=32; off>0; off>>=1) ss += __shfl_xor(ss, off, 64);
  const float rs = rsqrtf(ss*(1.f/1024.f) + 1e-6f);
  bf16x8 o0, o1;
  #pragma unroll
  for (int u=0;u<8;u++){
    o0[u] = f2bf(f0[u]*rs*nw[l*8+u]);
    o1[u] = f2bf(f1[u]*rs*nw[512+l*8+u]);
  }
  *(bf16x8*)(ON + tok*1024 + l*8) = o0;
  *(bf16x8*)(ON + tok*1024 + 512 + l*8) = o1;
}

// ----------------------------------------------------------------
extern "C" void kernel_launch(void* const* d_in, const int* in_sizes, int n_in,
                              void* d_out, int out_size, void* d_ws, size_t ws_size,
                              hipStream_t stream)
{
  (void)in_sizes; (void)n_in; (void)out_size;
  const float* x  = (const float*)d_in[0];
  const float* Wq = (const float*)d_in[1];
  const float* Wk = (const float*)d_in[2];
  const float* Wv = (const float*)d_in[3];
  const float* Wo = (const float*)d_in[4];
  const float* Wf = (const float*)d_in[5];
  const float* de = (const float*)d_in[6];
  const float* nw = (const float*)d_in[7];
  float* out = (float*)d_out;
  char* ws = (char*)d_ws;
  if (ws_size < 379633664u) return;   // need ~380MB scratch

  u16*   XBF  = (u16*)(ws + 0);              // x bf16 [32768][1024]; later reused as BT (f32)
  u16*   WQKV = (u16*)(ws + 67108864);       // [3072][1024]
  u16*   WOBF = (u16*)(ws + 73400320);       // [1024][1024]
  u16*   WFBF = (u16*)(ws + 75497472);       // [16][1024]
  u16*   QBUF = (u16*)(ws + 75530240);       // q -> qg -> o_norm  [32768][1024]
  u16*   KTB  = (u16*)(ws + 142639104);      // k^T [1024][32768]
  u16*   VTB  = (u16*)(ws + 209747968);      // v^T [1024][32768]
  u16*   OBUF = (u16*)(ws + 276856832);      // o   [32768][1024]
  float* LOGF = (float*)(ws + 343965696);    // [32768][16]
  float* TOTS = (float*)(ws + 346062848);    // [64][64]
  u16*   STB  = (u16*)(ws + 346079232);      // [64][4][16][4096] bf16
  float* BTF  = (float*)XBF;                 // [64][4][16][4096] f32

  cvt_kernel<<<16384, 256, 0, stream>>>(x, XBF);
  cvt_kernel<<<512, 256, 0, stream>>>(Wq, WQKV);
  cvt_kernel<<<512, 256, 0, stream>>>(Wk, WQKV + 1048576);
  cvt_kernel<<<512, 256, 0, stream>>>(Wv, WQKV + 2097152);
  cvt_kernel<<<512, 256, 0, stream>>>(Wo, WOBF);
  cvt_kernel<<<8, 256, 0, stream>>>(Wf, WFBF);

  gemm_bt<0><<<dim3(24, 256), 256, 0, stream>>>(XBF, WQKV, QBUF, KTB, VTB, nullptr);
  logf_kernel<<<512, 256, 0, stream>>>(XBF, WFBF, de, LOGF);
  intra_kernel<<<dim3(64, 64), 256, 0, stream>>>(QBUF, KTB, VTB, LOGF, TOTS, OBUF, BTF);
  scan_kernel<<<256, 256, 0, stream>>>(BTF, TOTS, STB);
  inter_kernel<<<dim3(64, 64), 256, 0, stream>>>(QBUF, STB, OBUF);
  rmsnorm_kernel<<<8192, 256, 0, stream>>>(OBUF, nw, QBUF);
  gemm_bt<1><<<dim3(8, 256), 256, 0, stream>>>(QBUF, WOBF, nullptr, nullptr, nullptr, out);
}

// Round 5
// 795.971 us; speedup vs baseline: 1.1189x; 1.1189x over previous
//
#include <hip/hip_runtime.h>

typedef unsigned short u16;
typedef __attribute__((ext_vector_type(8))) short bf16x8;
typedef __attribute__((ext_vector_type(4))) short bf16x4;
typedef __attribute__((ext_vector_type(4))) float f32x4;

#define MFMA16(a,b,c) __builtin_amdgcn_mfma_f32_16x16x32_bf16(a,b,c,0,0,0)

__device__ __forceinline__ float bf2f(short s){
  return __uint_as_float(((unsigned)(u16)s) << 16);
}
__device__ __forceinline__ short f2bf(float f){
  unsigned u = __float_as_uint(f);
  return (short)((u + 0x7FFFu + ((u >> 16) & 1u)) >> 16);
}
__device__ __forceinline__ void gload16(const void* g, void* l){
  __builtin_amdgcn_global_load_lds((const __attribute__((address_space(1))) unsigned int*)g,
                                   (__attribute__((address_space(3))) unsigned int*)l, 16, 0, 0);
}
__device__ __forceinline__ float silu_f(float v){ return v / (1.f + __expf(-v)); }

#define FENCE asm volatile("" ::: "memory")
#define BAR   do{ FENCE; __builtin_amdgcn_s_barrier(); FENCE; }while(0)
#define LGKM0 do{ asm volatile("s_waitcnt lgkmcnt(0)" ::: "memory"); __builtin_amdgcn_sched_barrier(0); }while(0)

// ---------------------------------------------------------------- fp32 -> bf16
__global__ __launch_bounds__(256) void cvt_kernel(const float* __restrict__ s, u16* __restrict__ d){
  size_t i = ((size_t)blockIdx.x*256 + threadIdx.x)*8;
  float4 a = *(const float4*)(s+i);
  float4 b = *(const float4*)(s+i+4);
  bf16x8 o;
  o[0]=f2bf(a.x); o[1]=f2bf(a.y); o[2]=f2bf(a.z); o[3]=f2bf(a.w);
  o[4]=f2bf(b.x); o[5]=f2bf(b.y); o[6]=f2bf(b.z); o[7]=f2bf(b.w);
  *(bf16x8*)(d+i) = o;
}

// ---------------------------------------------------------------- 256x256 8-phase GEMM  C = A * B^T
// A[M][1024], Bw[N][1024] bf16. BK=64, 16 K-tiles, 512 threads (8 waves 2x4),
// LDS 128KB: A0@0 A1@32K B0@64K B1@96K, each [256][64] bf16, XOR-swizzled
// (byte: c16 ^= row&7) via pre-swizzled global source + swizzled ds_read.
// Schedule per tile u (4 phases, one C-quadrant of 2m x 4n x 2k = 16 MFMA each):
//   ph0: ds_read B-all(8)+A(4); stage Ah0(u+1); BAR; lgkm0; MFMA; BAR
//   ph1: ds_read A(4);          stage Ah1(u+1); BAR; lgkm0; MFMA; BAR
//   ph2: ds_read A(4);          stage Bh0(u+2); BAR; lgkm0; MFMA; BAR
//   ph3: ds_read A(4);          stage Bh1(u+2); vmcnt(4); BAR; lgkm0; MFMA; BAR
// Boundary vmcnt(4) leaves B(u+2)'s 4 loads in flight (counted, never 0 until tail).
// MODE 0: nblk 0-3 -> q (silu), 4-7 -> kT (silu, [ch][tok]), 8-11 -> vT ([ch][tok])
// MODE 1: fp32 out [tok][ch]
template<int MODE>
__global__ __launch_bounds__(512) void gemm256(
    const u16* __restrict__ A, const u16* __restrict__ Bw,
    u16* __restrict__ qo, u16* __restrict__ kTo, u16* __restrict__ vTo,
    float* __restrict__ outf)
{
  __shared__ __align__(16) char smem[131072];
  const int tid = threadIdx.x, l = tid & 63, wv = tid >> 6;
  const int wr = wv >> 2, wc = wv & 3;
  const int m0 = blockIdx.y << 8, n0 = blockIdx.x << 8;
  const int sr = (wv << 3) + (l >> 3);   // staging row 0..63 within 64-row issue block
  const int sc = l & 7;                  // staging col16
  const int lk = l >> 4, ln = l & 15;

  f32x4 acc[8][4] = {};

  auto stA = [&](int u, int h){
    const u16* src = A + (size_t)(m0 + h*128)*1024 + u*64;
    char* dst = smem + (u&1)*32768 + h*16384 + wv*1024;
    #pragma unroll
    for (int i=0;i<2;i++){
      const int r = i*64 + sr;
      gload16(src + (size_t)r*1024 + ((sc ^ (r&7))<<3), dst + i*8192);
    }
  };
  auto stB = [&](int u, int h){
    const u16* src = Bw + (size_t)(n0 + h*128)*1024 + u*64;
    char* dst = smem + 65536 + (u&1)*32768 + h*16384 + wv*1024;
    #pragma unroll
    for (int i=0;i<2;i++){
      const int r = i*64 + sr;
      gload16(src + (size_t)r*1024 + ((sc ^ (r&7))<<3), dst + i*8192);
    }
  };
  auto ldA = [&](int bsel, int row, int ks)->bf16x8 {
    const int c16 = ((ks<<2) + lk) ^ (row & 7);
    return *(const bf16x8*)(smem + bsel + row*128 + (c16<<4));
  };
  auto ldB = [&](int bsel, int row, int ks)->bf16x8 {
    const int c16 = ((ks<<2) + lk) ^ (row & 7);
    return *(const bf16x8*)(smem + 65536 + bsel + row*128 + (c16<<4));
  };

  // prologue: A(0), B(0), B(1); leave B(1) (4 loads) in flight
  stA(0,0); stA(0,1); stB(0,0); stB(0,1); stB(1,0); stB(1,1);
  asm volatile("s_waitcnt vmcnt(4)" ::: "memory");
  BAR;

  bf16x8 brg[4][2];
  #pragma unroll 1
  for (int u=0; u<16; ++u){
    const int bsel = (u&1)*32768;
    // ---------------- phase 0 (m-frags 0,1 + load all B)
    {
      #pragma unroll
      for (int n=0;n<4;n++){
        brg[n][0] = ldB(bsel, wc*64 + n*16 + ln, 0);
        brg[n][1] = ldB(bsel, wc*64 + n*16 + ln, 1);
      }
      bf16x8 a00 = ldA(bsel, wr*128 +  0 + ln, 0);
      bf16x8 a01 = ldA(bsel, wr*128 +  0 + ln, 1);
      bf16x8 a10 = ldA(bsel, wr*128 + 16 + ln, 0);
      bf16x8 a11 = ldA(bsel, wr*128 + 16 + ln, 1);
      if (u+1 < 16) stA(u+1, 0);
      BAR; LGKM0;
      __builtin_amdgcn_s_setprio(1);
      #pragma unroll
      for (int n=0;n<4;n++){
        acc[0][n] = MFMA16(a00, brg[n][0], acc[0][n]);
        acc[0][n] = MFMA16(a01, brg[n][1], acc[0][n]);
        acc[1][n] = MFMA16(a10, brg[n][0], acc[1][n]);
        acc[1][n] = MFMA16(a11, brg[n][1], acc[1][n]);
      }
      __builtin_amdgcn_s_setprio(0);
      BAR;
    }
    // ---------------- phase 1 (m-frags 2,3)
    {
      bf16x8 a00 = ldA(bsel, wr*128 + 32 + ln, 0);
      bf16x8 a01 = ldA(bsel, wr*128 + 32 + ln, 1);
      bf16x8 a10 = ldA(bsel, wr*128 + 48 + ln, 0);
      bf16x8 a11 = ldA(bsel, wr*128 + 48 + ln, 1);
      if (u+1 < 16) stA(u+1, 1);
      BAR; LGKM0;
      __builtin_amdgcn_s_setprio(1);
      #pragma unroll
      for (int n=0;n<4;n++){
        acc[2][n] = MFMA16(a00, brg[n][0], acc[2][n]);
        acc[2][n] = MFMA16(a01, brg[n][1], acc[2][n]);
        acc[3][n] = MFMA16(a10, brg[n][0], acc[3][n]);
        acc[3][n] = MFMA16(a11, brg[n][1], acc[3][n]);
      }
      __builtin_amdgcn_s_setprio(0);
      BAR;
    }
    // ---------------- phase 2 (m-frags 4,5)
    {
      bf16x8 a00 = ldA(bsel, wr*128 + 64 + ln, 0);
      bf16x8 a01 = ldA(bsel, wr*128 + 64 + ln, 1);
      bf16x8 a10 = ldA(bsel, wr*128 + 80 + ln, 0);
      bf16x8 a11 = ldA(bsel, wr*128 + 80 + ln, 1);
      if (u+2 < 16) stB(u+2, 0);
      BAR; LGKM0;
      __builtin_amdgcn_s_setprio(1);
      #pragma unroll
      for (int n=0;n<4;n++){
        acc[4][n] = MFMA16(a00, brg[n][0], acc[4][n]);
        acc[4][n] = MFMA16(a01, brg[n][1], acc[4][n]);
        acc[5][n] = MFMA16(a10, brg[n][0], acc[5][n]);
        acc[5][n] = MFMA16(a11, brg[n][1], acc[5][n]);
      }
      __builtin_amdgcn_s_setprio(0);
      BAR;
    }
    // ---------------- phase 3 (m-frags 6,7) + tile boundary wait
    {
      bf16x8 a00 = ldA(bsel, wr*128 +  96 + ln, 0);
      bf16x8 a01 = ldA(bsel, wr*128 +  96 + ln, 1);
      bf16x8 a10 = ldA(bsel, wr*128 + 112 + ln, 0);
      bf16x8 a11 = ldA(bsel, wr*128 + 112 + ln, 1);
      if (u+2 < 16) stB(u+2, 1);
      if (u <= 13)      { asm volatile("s_waitcnt vmcnt(4)" ::: "memory"); }
      else if (u == 14) { asm volatile("s_waitcnt vmcnt(0)" ::: "memory"); }
      BAR; LGKM0;
      __builtin_amdgcn_s_setprio(1);
      #pragma unroll
      for (int n=0;n<4;n++){
        acc[6][n] = MFMA16(a00, brg[n][0], acc[6][n]);
        acc[6][n] = MFMA16(a01, brg[n][1], acc[6][n]);
        acc[7][n] = MFMA16(a10, brg[n][0], acc[7][n]);
        acc[7][n] = MFMA16(a11, brg[n][1], acc[7][n]);
      }
      __builtin_amdgcn_s_setprio(0);
      BAR;
    }
  }

  // epilogue: D layout col = ln, row = lk*4 + r
  if constexpr (MODE == 1){
    #pragma unroll
    for (int m=0;m<8;m++){
      const int tok = m0 + wr*128 + m*16 + lk*4;
      #pragma unroll
      for (int n=0;n<4;n++){
        const int ch = n0 + wc*64 + n*16 + ln;
        #pragma unroll
        for (int r=0;r<4;r++)
          outf[(size_t)(tok+r)*1024 + ch] = acc[m][n][r];
      }
    }
  } else {
    const int nblk = blockIdx.x;
    if (nblk < 4){
      #pragma unroll
      for (int m=0;m<8;m++){
        const int tok = m0 + wr*128 + m*16 + lk*4;
        #pragma unroll
        for (int n=0;n<4;n++){
          const int ch = nblk*256 + wc*64 + n*16 + ln;
          #pragma unroll
          for (int r=0;r<4;r++)
            qo[(size_t)(tok+r)*1024 + ch] = (u16)f2bf(silu_f(acc[m][n][r]));
        }
      }
    } else {
      const bool dos = nblk < 8;            // k gets silu, v not
      u16* T = dos ? kTo : vTo;
      const int cb = (nblk & 3) << 8;
      #pragma unroll
      for (int m=0;m<8;m++){
        const int tok0 = m0 + wr*128 + m*16 + lk*4;
        #pragma unroll
        for (int n=0;n<4;n++){
          const int ch = cb + wc*64 + n*16 + ln;
          bf16x4 pk;
          #pragma unroll
          for (int r=0;r<4;r++){
            float v = acc[m][n][r];
            if (dos) v = silu_f(v);
            pk[r] = f2bf(v);
          }
          *(bf16x4*)(T + (size_t)ch*32768 + tok0) = pk;   // transposed [ch][tok]
        }
      }
    }
  }
}

// ---------------------------------------------------------------- log_f = logsigmoid(x @ Wf^T + delta)
__global__ __launch_bounds__(256) void logf_kernel(
  const u16* __restrict__ xbf, const u16* __restrict__ wf,
  const float* __restrict__ delta, float* __restrict__ lfo)
{
  const int tid = threadIdx.x, l = tid&63, wv = tid>>6;
  const int arow = blockIdx.x*64 + wv*16 + (l&15);
  const u16* xr  = xbf + (size_t)arow*1024 + ((l>>4)<<3);
  const u16* wr_ = wf  + (size_t)(l&15)*1024 + ((l>>4)<<3);
  f32x4 acc = {0.f,0.f,0.f,0.f};
  #pragma unroll 4
  for (int kk=0; kk<32; ++kk){
    bf16x8 a = *(const bf16x8*)(xr  + kk*32);
    bf16x8 b = *(const bf16x8*)(wr_ + kk*32);
    acc = MFMA16(a,b,acc);
  }
  const int h = l&15;
  const float dl = delta[h];
  const int trow = blockIdx.x*64 + wv*16 + ((l>>4)<<2);
  #pragma unroll
  for (int r=0;r<4;r++){
    float z = acc[r] + dl;
    lfo[(size_t)(trow + r)*16 + h] = fminf(z, 0.f) - log1pf(__expf(-fabsf(z)));
  }
}

// ---------------------------------------------------------------- per-chunk intra kernel
// LDS map: [0,16K) s_q [128][64] swz8 ; [16K,32K) s_k [128][64] swz8 (built by identity-mfma)
//          [32K,48K) s_kT [64][128] swz16 ; [48K,64K) s_vT [64][128] swz16
//          AA overlays [0,32K) as [128][128] bf16 swz16 ; Bc-bounce overlays [32K,48K) f32 [64][64] swz16
#define P2_SK  16384
#define P2_SKT 32768
#define P2_SVT 49152
__global__ __launch_bounds__(256) void intra_kernel(
  u16* __restrict__ q,
  const u16* __restrict__ kT, const u16* __restrict__ vT,
  const float* __restrict__ lfin, float* __restrict__ tots,
  u16* __restrict__ O, float* __restrict__ BT)
{
  __shared__ __align__(16) char smem[67072];
  float* s_lf = (float*)(smem + 65536);
  float* s_e  = (float*)(smem + 66048);
  float* s_en = (float*)(smem + 66560);
  const int c = blockIdx.x, bh = blockIdx.y;
  const int b = bh >> 4, h = bh & 15;
  const int tid = threadIdx.x, l = tid&63, wv = tid>>6;
  const size_t tok0 = (size_t)b*8192 + (size_t)c*128;

  // Phase A: inclusive cumsum of log_f, gates
  if (tid < 128) s_lf[tid] = lfin[(tok0 + tid)*16 + h];
  __syncthreads();
  #pragma unroll
  for (int off=1; off<128; off<<=1){
    float v = 0.f;
    if (tid < 128) v = s_lf[tid] + ((tid >= off) ? s_lf[tid-off] : 0.f);
    __syncthreads();
    if (tid < 128) s_lf[tid] = v;
    __syncthreads();
  }
  if (tid < 128){ const float lv = s_lf[tid]; s_e[tid] = __expf(lv); s_en[tid] = __expf(-lv); }
  if (tid == 0) tots[((size_t)b*16 + h)*64 + c] = s_lf[127];
  __syncthreads();

  // Phase B: stage q (and write qg=q*e[j] back), kT*en[j] -> s_kT, vT -> s_vT
  {
    u16* qb = q + tok0*1024 + h*64;
    #pragma unroll
    for (int it=0; it<4; ++it){
      const int cid = it*256 + tid;
      const int j = cid >> 3, d0 = (cid&7)*8;
      bf16x8 v = *(const bf16x8*)(qb + (size_t)j*1024 + d0);
      *(bf16x8*)(smem + j*128 + ((d0*2) ^ ((j&7)<<4))) = v;
      const float ej = s_e[j];
      bf16x8 o;
      #pragma unroll
      for (int u=0;u<8;u++) o[u] = f2bf(bf2f(v[u]) * ej);
      *(bf16x8*)(qb + (size_t)j*1024 + d0) = o;
    }
    const u16* kb_ = kT + (size_t)(h*64)*32768 + tok0;
    const u16* vb_ = vT + (size_t)(h*64)*32768 + tok0;
    #pragma unroll
    for (int it=0; it<4; ++it){
      const int cid = it*256 + tid;
      const int d = cid >> 4, j0 = (cid&15)*8;
      bf16x8 kv = *(const bf16x8*)(kb_ + (size_t)d*32768 + j0);
      bf16x8 vv = *(const bf16x8*)(vb_ + (size_t)d*32768 + j0);
      bf16x8 ks;
      #pragma unroll
      for (int u=0;u<8;u++) ks[u] = f2bf(bf2f(kv[u]) * s_en[j0+u]);
      *(bf16x8*)(smem + P2_SKT + d*256 + ((j0*2) ^ ((d&15)<<4))) = ks;
      *(bf16x8*)(smem + P2_SVT + d*256 + ((j0*2) ^ ((d&15)<<4))) = vv;
    }
  }
  __syncthreads();

  // Phase C: identity-MFMA transpose s_kT[64][128] -> s_k[128][64]
  #pragma unroll
  for (int nn=0; nn<2; ++nn){
    const int nt = wv*2 + nn;                 // j-tile 0..7
    const int kk = nt >> 1;
    const int ustar = ((nt&1)<<4) + (l&15) - ((l>>4)<<3);
    bf16x8 ib;
    #pragma unroll
    for (int u=0;u<8;u++) ib[u] = (u == ustar) ? (short)0x3F80 : (short)0;
    const int jb = (kk*32 + ((l>>4)<<3))*2;
    #pragma unroll
    for (int mt=0; mt<4; ++mt){
      const int d = mt*16 + (l&15);
      bf16x8 af = *(const bf16x8*)(smem + P2_SKT + d*256 + (jb ^ ((d&15)<<4)));
      f32x4 dd = {0.f,0.f,0.f,0.f};
      dd = MFMA16(af, ib, dd);
      const int jj = nt*16 + (l&15);
      const int d0 = mt*16 + ((l>>4)<<2);
      bf16x4 pk;
      #pragma unroll
      for (int r=0;r<4;r++) pk[r] = f2bf(dd[r]);
      *(bf16x4*)(smem + P2_SK + jj*128 + ((d0*2) ^ ((jj&7)<<4))) = pk;
    }
  }
  __syncthreads();

  // Phase D: D1 = ks * q^T  (D1[j][i] = A[i][j]*en[j]); wave w owns j-tiles {w, 7-w}
  f32x4 acc1[2][8] = {};
  const int jt0 = wv, jt1 = 7 - wv;
  #pragma unroll
  for (int ks=0; ks<2; ++ks){
    const int kb = (ks*32 + ((l>>4)<<3))*2;
    bf16x8 aq[8];
    #pragma unroll
    for (int nt=0;nt<8;nt++){
      const int i = nt*16 + (l&15);
      aq[nt] = *(const bf16x8*)(smem + i*128 + (kb ^ ((i&7)<<4)));
    }
    const int jr0 = jt0*16 + (l&15), jr1 = jt1*16 + (l&15);
    bf16x8 ak0 = *(const bf16x8*)(smem + P2_SK + jr0*128 + (kb ^ ((jr0&7)<<4)));
    bf16x8 ak1 = *(const bf16x8*)(smem + P2_SK + jr1*128 + (kb ^ ((jr1&7)<<4)));
    #pragma unroll
    for (int nt=0;nt<8;nt++){
      if (nt >= jt0) acc1[0][nt] = MFMA16(ak0, aq[nt], acc1[0][nt]);
      if (nt >= jt1) acc1[1][nt] = MFMA16(ak1, aq[nt], acc1[1][nt]);
    }
  }
  __syncthreads();          // all reads of [0,32K) done

  // Phase D2: gate (* e[i], tril mask), write AA[i][j] bf16 over [0,32K)
  #pragma unroll
  for (int jj=0;jj<2;jj++){
    const int jt = (jj==0)? jt0 : jt1;
    const int j0 = jt*16 + ((l>>4)<<2);
    #pragma unroll
    for (int nt=0;nt<8;nt++){
      const int i = nt*16 + (l&15);
      bf16x4 pk;
      if (nt < jt){
        #pragma unroll
        for (int r=0;r<4;r++) pk[r] = (short)0;
      } else {
        const float ei = s_e[i];
        #pragma unroll
        for (int r=0;r<4;r++){
          float v = acc1[jj][nt][r] * ei;
          if (nt == jt && (j0 + r) > i) v = 0.f;
          pk[r] = f2bf(v);
        }
      }
      *(bf16x4*)(smem + i*256 + ((j0*2) ^ ((i&15)<<4))) = pk;
    }
  }
  __syncthreads();

  // Phase E: o_intra^T[e][i] = sum_j vT[e][j]*AA[i][j]  (wave owns i-tiles {w,7-w})
  //          Bc[d][e]        = sum_j kT[d][j]*vT[e][j]  (wave owns d-tile w)
  {
    const int nt0 = wv, nt1 = 7 - wv;
    f32x4 oacc[2][4] = {};
    f32x4 bcacc[4] = {};
    #pragma unroll
    for (int kk=0; kk<4; ++kk){
      const int jb = (kk*32 + ((l>>4)<<3))*2;
      bf16x8 av[4];
      #pragma unroll
      for (int mt=0;mt<4;mt++){
        const int e = mt*16 + (l&15);
        av[mt] = *(const bf16x8*)(smem + P2_SVT + e*256 + (jb ^ ((e&15)<<4)));
      }
      const int dr = wv*16 + (l&15);
      bf16x8 akt = *(const bf16x8*)(smem + P2_SKT + dr*256 + (jb ^ ((dr&15)<<4)));
      #pragma unroll
      for (int mt=0;mt<4;mt++) bcacc[mt] = MFMA16(akt, av[mt], bcacc[mt]);
      const int i0 = nt0*16 + (l&15);
      if (kk <= (nt0>>1)){
        bf16x8 ba = *(const bf16x8*)(smem + i0*256 + (jb ^ ((i0&15)<<4)));
        #pragma unroll
        for (int mt=0;mt<4;mt++) oacc[0][mt] = MFMA16(av[mt], ba, oacc[0][mt]);
      }
      const int i1 = nt1*16 + (l&15);
      if (kk <= (nt1>>1)){
        bf16x8 ba = *(const bf16x8*)(smem + i1*256 + (jb ^ ((i1&15)<<4)));
        #pragma unroll
        for (int mt=0;mt<4;mt++) oacc[1][mt] = MFMA16(av[mt], ba, oacc[1][mt]);
      }
    }
    // store o_intra (bf16, 8B packed along e)
    #pragma unroll
    for (int jj=0;jj<2;jj++){
      const int nt = (jj==0)?nt0:nt1;
      const int i = nt*16 + (l&15);
      u16* orow = O + (tok0 + i)*1024 + h*64;
      #pragma unroll
      for (int mt=0;mt<4;mt++){
        const int e0 = mt*16 + ((l>>4)<<2);
        bf16x4 pk;
        #pragma unroll
        for (int r=0;r<4;r++) pk[r] = f2bf(oacc[jj][mt][r]);
        *(bf16x4*)(orow + e0) = pk;
      }
    }
    __syncthreads();    // s_kT reads done
    // E2: Bc -> LDS bounce (layout [e][d] f32, swizzled) over s_kT region, then coalesced store
    #pragma unroll
    for (int nt2=0; nt2<4; ++nt2){
      const int e = nt2*16 + (l&15);
      const int d0 = wv*16 + ((l>>4)<<2);
      *(f32x4*)(smem + P2_SKT + e*256 + ((d0*4) ^ ((e&15)<<4))) = bcacc[nt2];
    }
    __syncthreads();
    float* BTo = BT + (((size_t)c*4 + b)*16 + h)*4096;
    #pragma unroll
    for (int u=0;u<4;u++){
      const int fb = tid*64 + u*16;
      const int e = fb >> 8, wi = fb & 255;
      f32x4 vvv = *(const f32x4*)(smem + P2_SKT + e*256 + (wi ^ ((e&15)<<4)));
      *(f32x4*)((char*)BTo + fb) = vvv;
    }
  }
}

// ---------------------------------------------------------------- sequential scalar-decay scan
// BT/ST layout: [c][b][h][e*64+d] ; ST[c] = state BEFORE chunk c (bf16); S <- e^tot * (S + Bc)
__global__ __launch_bounds__(256) void scan_kernel(
  const float* __restrict__ BT, const float* __restrict__ tots, u16* __restrict__ ST)
{
  const int blk = blockIdx.x;
  const int bh = blk >> 2, qt = blk & 3;
  const int tid = threadIdx.x;
  __shared__ float s_tot[64];
  if (tid < 64) s_tot[tid] = tots[(size_t)bh*64 + tid];
  __syncthreads();
  const int flat = qt*1024 + tid*4;
  const float* bp = BT + (size_t)bh*4096 + flat;
  u16* sp = ST + (size_t)bh*4096 + flat;
  const size_t cs = 262144;
  f32x4 S = {0.f,0.f,0.f,0.f};
  f32x4 cur = *(const f32x4*)bp;
  f32x4 nxt = *(const f32x4*)(bp + cs);
  for (int cc=0; cc<64; ++cc){
    bf16x4 pk;
    #pragma unroll
    for (int r=0;r<4;r++) pk[r] = f2bf(S[r]);
    *(bf16x4*)(sp + (size_t)cc*cs) = pk;
    const float et = __expf(s_tot[cc]);
    #pragma unroll
    for (int r=0;r<4;r++) S[r] = et*(S[r] + cur[r]);
    cur = nxt;
    if (cc + 2 < 64) nxt = *(const f32x4*)(bp + (size_t)(cc+2)*cs);
  }
}

// ---------------------------------------------------------------- o_inter = qg @ S, RMW into O
__global__ __launch_bounds__(256) void inter_kernel(
  const u16* __restrict__ qg, const u16* __restrict__ ST, u16* __restrict__ O)
{
  __shared__ __align__(16) char smem[24576];   // s_qg [128][64] swz8 @0 ; s_ST [64][64] swz8 @16384
  const int c = blockIdx.x, bh = blockIdx.y;
  const int b = bh>>4, h = bh&15;
  const int tid = threadIdx.x, l = tid&63, wv = tid>>6;
  const size_t tok0 = (size_t)b*8192 + (size_t)c*128;
  const u16* qb = qg + tok0*1024 + h*64;
  #pragma unroll
  for (int it=0; it<4; ++it){
    const int cid = it*256 + tid, j = cid>>3, d0 = (cid&7)*8;
    bf16x8 v = *(const bf16x8*)(qb + (size_t)j*1024 + d0);
    *(bf16x8*)(smem + j*128 + ((d0*2) ^ ((j&7)<<4))) = v;
  }
  const u16* stb = ST + (((size_t)c*4 + b)*16 + h)*4096;
  #pragma unroll
  for (int it=0; it<2; ++it){
    const int cid = it*256 + tid, e = cid>>3, d0 = (cid&7)*8;
    bf16x8 v = *(const bf16x8*)(stb + (size_t)e*64 + d0);
    *(bf16x8*)(smem + 16384 + e*128 + ((d0*2) ^ ((e&7)<<4))) = v;
  }
  __syncthreads();
  f32x4 acc[8] = {};
  #pragma unroll
  for (int ks=0; ks<2; ++ks){
    const int kb = (ks*32 + ((l>>4)<<3))*2;
    const int er = wv*16 + (l&15);
    bf16x8 as = *(const bf16x8*)(smem + 16384 + er*128 + (kb ^ ((er&7)<<4)));
    #pragma unroll
    for (int nt=0;nt<8;nt++){
      const int ir = nt*16 + (l&15);
      bf16x8 bq = *(const bf16x8*)(smem + ir*128 + (kb ^ ((ir&7)<<4)));
      acc[nt] = MFMA16(as, bq, acc[nt]);
    }
  }
  const int e0 = wv*16 + ((l>>4)<<2);
  #pragma unroll
  for (int nt=0;nt<8;nt++){
    const int i = nt*16 + (l&15);
    u16* op = O + (tok0 + i)*1024 + h*64 + e0;
    bf16x4 cu = *(const bf16x4*)op;
    bf16x4 pk;
    #pragma unroll
    for (int r=0;r<4;r++) pk[r] = f2bf(bf2f(cu[r]) + acc[nt][r]);
    *(bf16x4*)op = pk;
  }
}

// ---------------------------------------------------------------- RMSNorm (one wave per token)
__global__ __launch_bounds__(256) void rmsnorm_kernel(
  const u16* __restrict__ O, const float* __restrict__ nw, u16* __restrict__ ON)
{
  const int tid = threadIdx.x, l = tid&63, wv = tid>>6;
  const size_t tok = (size_t)blockIdx.x*4 + wv;
  const u16* row = O + tok*1024;
  bf16x8 v0 = *(const bf16x8*)(row + l*8);
  bf16x8 v1 = *(const bf16x8*)(row + 512 + l*8);
  float f0[8], f1[8];
  float ss = 0.f;
  #pragma unroll
  for (int u=0;u<8;u++){ f0[u]=bf2f(v0[u]); f1[u]=bf2f(v1[u]); ss += f0[u]*f0[u] + f1[u]*f1[u]; }
  #pragma unroll
  for (int off=32; off>0; off>>=1) ss += __shfl_xor(ss, off, 64);
  const float rs = rsqrtf(ss*(1.f/1024.f) + 1e-6f);
  bf16x8 o0, o1;
  #pragma unroll
  for (int u=0;u<8;u++){
    o0[u] = f2bf(f0[u]*rs*nw[l*8+u]);
    o1[u] = f2bf(f1[u]*rs*nw[512+l*8+u]);
  }
  *(bf16x8*)(ON + tok*1024 + l*8) = o0;
  *(bf16x8*)(ON + tok*1024 + 512 + l*8) = o1;
}

// ----------------------------------------------------------------
extern "C" void kernel_launch(void* const* d_in, const int* in_sizes, int n_in,
                              void* d_out, int out_size, void* d_ws, size_t ws_size,
                              hipStream_t stream)
{
  (void)in_sizes; (void)n_in; (void)out_size;
  const float* x  = (const float*)d_in[0];
  const float* Wq = (const float*)d_in[1];
  const float* Wk = (const float*)d_in[2];
  const float* Wv = (const float*)d_in[3];
  const float* Wo = (const float*)d_in[4];
  const float* Wf = (const float*)d_in[5];
  const float* de = (const float*)d_in[6];
  const float* nw = (const float*)d_in[7];
  float* out = (float*)d_out;
  char* ws = (char*)d_ws;
  if (ws_size < 379633664u) return;   // need ~380MB scratch

  u16*   XBF  = (u16*)(ws + 0);              // x bf16 [32768][1024]; later reused as BT (f32)
  u16*   WQKV = (u16*)(ws + 67108864);       // [3072][1024]
  u16*   WOBF = (u16*)(ws + 73400320);       // [1024][1024]
  u16*   WFBF = (u16*)(ws + 75497472);       // [16][1024]
  u16*   QBUF = (u16*)(ws + 75530240);       // q -> qg -> o_norm  [32768][1024]
  u16*   KTB  = (u16*)(ws + 142639104);      // k^T [1024][32768]
  u16*   VTB  = (u16*)(ws + 209747968);      // v^T [1024][32768]
  u16*   OBUF = (u16*)(ws + 276856832);      // o   [32768][1024]
  float* LOGF = (float*)(ws + 343965696);    // [32768][16]
  float* TOTS = (float*)(ws + 346062848);    // [64][64]
  u16*   STB  = (u16*)(ws + 346079232);      // [64][4][16][4096] bf16
  float* BTF  = (float*)XBF;                 // [64][4][16][4096] f32

  cvt_kernel<<<16384, 256, 0, stream>>>(x, XBF);
  cvt_kernel<<<512, 256, 0, stream>>>(Wq, WQKV);
  cvt_kernel<<<512, 256, 0, stream>>>(Wk, WQKV + 1048576);
  cvt_kernel<<<512, 256, 0, stream>>>(Wv, WQKV + 2097152);
  cvt_kernel<<<512, 256, 0, stream>>>(Wo, WOBF);
  cvt_kernel<<<8, 256, 0, stream>>>(Wf, WFBF);

  gemm256<0><<<dim3(12, 128), 512, 0, stream>>>(XBF, WQKV, QBUF, KTB, VTB, nullptr);
  logf_kernel<<<512, 256, 0, stream>>>(XBF, WFBF, de, LOGF);
  intra_kernel<<<dim3(64, 64), 256, 0, stream>>>(QBUF, KTB, VTB, LOGF, TOTS, OBUF, BTF);
  scan_kernel<<<256, 256, 0, stream>>>(BTF, TOTS, STB);
  inter_kernel<<<dim3(64, 64), 256, 0, stream>>>(QBUF, STB, OBUF);
  rmsnorm_kernel<<<8192, 256, 0, stream>>>(OBUF, nw, QBUF);
  gemm256<1><<<dim3(4, 128), 512, 0, stream>>>(QBUF, WOBF, nullptr, nullptr, nullptr, out);
}